// Round 7
// baseline (693.623 us; speedup 1.0000x reference)
//
#include <hip/hip_runtime.h>
#include <hip/hip_bf16.h>
#include <hip/hip_fp16.h>
#include <hip/hip_cooperative_groups.h>

namespace cg = cooperative_groups;

// GCN forward on MI355X.
// x:[50000,256] f32, edges: 800000 (src,dst,w), W1:[256,128], W2:[128,128], W3:[128,64]
// out = concat(Y[50000,64], x3[50000,128]) f32
//
// Primary: single cooperative mega-kernel (grid sized via occupancy API,
//          return code checked). Fallback: 6-dispatch pipeline (round-5
//          structure) sharing the same device bodies.
// Phases:
//   P0: zero cnt || pack W1/W2/W3 -> bf16 hi/lo (MFMA frag order)
//   P1: gemm1 h1 = x@W1 -> bf16  INTERLEAVED {gemm,fill,fill} with ell_fill
//       (4B ELL entries: u16 src | fp16 w)
//   P2: x1b = leaky(spmm(h1)) -> bf16
//   P3: h2 = x1b @ W2 -> bf16 (A exact bf16, 2-term)
//   P4: x3 = spmm(h2) -> d_out fp32
//   P5: Y = sigmoid(x3 @ W3) -> d_out fp32

constexpr int N_NODES = 50000;
constexpr int N_EDGES = 800000;
constexpr int NFEAT = 256;
constexpr int NHID = 128;
constexpr int NCLASS = 64;
constexpr int EW = 64;  // ELL width (Poisson(16) => P(deg>=64) ~ 1e-18)

constexpr int GB1 = (N_NODES + 31) / 32;            // 1563 gemm M-tiles
constexpr int EDGE_BLOCKS = (N_EDGES + 255) / 256;  // 3125
constexpr int NODE_BLOCKS = (N_NODES + 3) / 4;      // 12500

typedef __attribute__((ext_vector_type(8))) short short8;
typedef __attribute__((ext_vector_type(4))) float f32x4;

__device__ __forceinline__ unsigned short f32_to_bf16_rne(float f) {
  unsigned u = __float_as_uint(f);
  unsigned r = u + 0x7fffu + ((u >> 16) & 1u);
  return (unsigned short)(r >> 16);
}
__device__ __forceinline__ float bf16_to_f32(unsigned short s) {
  return __uint_as_float(((unsigned)s) << 16);
}

// ---------------------------------------------------------------------------
// Pack W[K][N] fp32 -> hi/lo bf16 in MFMA fragment order.
// Frag f = kb*(N/16) + nt; lane l holds 8 elems: k = kb*32+(l>>4)*8+j, n = nt*16+(l&15).
// ---------------------------------------------------------------------------
template <int K, int N>
__device__ __forceinline__ void pack_dev(const float* __restrict__ W,
                                         short* __restrict__ Bh,
                                         short* __restrict__ Bl, int blk) {
  int idx = blk * 256 + threadIdx.x;
  constexpr int NFRAG = (K / 32) * (N / 16);
  if (idx >= NFRAG * 64) return;
  int l = idx & 63;
  int f = idx >> 6;
  int kb = f / (N / 16), nt = f % (N / 16);
  int g = l >> 4;
  int n = nt * 16 + (l & 15);
#pragma unroll
  for (int j = 0; j < 8; ++j) {
    int k = kb * 32 + g * 8 + j;
    float v = W[(size_t)k * N + n];
    unsigned short h = f32_to_bf16_rne(v);
    Bh[((size_t)f * 64 + l) * 8 + j] = (short)h;
    Bl[((size_t)f * 64 + l) * 8 + j] = (short)f32_to_bf16_rne(v - bf16_to_f32(h));
  }
}

__device__ __forceinline__ void prep_body(int b, const float* __restrict__ W1,
                                          const float* __restrict__ W2,
                                          const float* __restrict__ W3, short* W1h,
                                          short* W1l, short* W2h, short* W2l,
                                          short* W3h, short* W3l,
                                          int* __restrict__ cnt) {
  if (b < 196) {
    int i = b * 256 + threadIdx.x;
    if (i < N_NODES) cnt[i] = 0;
  } else if (b < 212) {
    pack_dev<NFEAT, NHID>(W1, W1h, W1l, b - 196);
  } else if (b < 220) {
    pack_dev<NHID, NHID>(W2, W2h, W2l, b - 212);
  } else {
    pack_dev<NHID, NCLASS>(W3, W3h, W3l, b - 220);
  }
}

// ---------------------------------------------------------------------------
// MFMA GEMM body: C[M,N] = A[M,K] @ W[K,N]
// A_BF16=0: A fp32, split3 (Ah@Bh + Al@Bh + Ah@Bl).  A_BF16=1: A bf16 exact, 2-term.
// 4 waves/block; wave = 16 rows x N/2 cols. bx in [0, ceil(M/32)).
// ---------------------------------------------------------------------------
template <int K, int N, bool A_BF16, bool SIGMOID, bool OUT_BF16>
__device__ __forceinline__ void gemm_body(int bx, const void* __restrict__ Av,
                                          const short* __restrict__ Bh,
                                          const short* __restrict__ Bl,
                                          void* __restrict__ Cv, int M) {
  constexpr int WCOL = N / 2;
  constexpr int F = WCOL / 16;
  const int tid = threadIdx.x;
  const int wid = tid >> 6;
  const int lane = tid & 63;
  const int g = lane >> 4;
  const int brow = bx * 32 + (wid >> 1) * 16;
  const int col0 = (wid & 1) * WCOL;
  const int row_a = brow + (lane & 15);

  f32x4 acc[F];
#pragma unroll
  for (int i = 0; i < F; ++i) acc[i] = (f32x4){0.f, 0.f, 0.f, 0.f};

#pragma unroll
  for (int kb = 0; kb < K / 32; ++kb) {
    const int ca = kb * 32 + g * 8;
    short8 ah, al;
    if (A_BF16) {
      const unsigned short* A = (const unsigned short*)Av;
      if (row_a < M) {
        ah = *reinterpret_cast<const short8*>(A + (size_t)row_a * K + ca);
      } else {
        ah = (short8){0, 0, 0, 0, 0, 0, 0, 0};
      }
    } else {
      const float* A = (const float*)Av;
      float4 a0 = {0.f, 0.f, 0.f, 0.f}, a1 = {0.f, 0.f, 0.f, 0.f};
      if (row_a < M) {
        a0 = *reinterpret_cast<const float4*>(A + (size_t)row_a * K + ca);
        a1 = *reinterpret_cast<const float4*>(A + (size_t)row_a * K + ca + 4);
      }
      float av[8] = {a0.x, a0.y, a0.z, a0.w, a1.x, a1.y, a1.z, a1.w};
#pragma unroll
      for (int j = 0; j < 8; ++j) {
        float v = av[j];
        unsigned short h = f32_to_bf16_rne(v);
        ah[j] = (short)h;
        al[j] = (short)f32_to_bf16_rne(v - bf16_to_f32(h));
      }
    }
#pragma unroll
    for (int nt = 0; nt < F; ++nt) {
      int f = kb * (N / 16) + (col0 >> 4) + nt;
      short8 bh = *reinterpret_cast<const short8*>(Bh + ((size_t)f * 64 + lane) * 8);
      short8 bl = *reinterpret_cast<const short8*>(Bl + ((size_t)f * 64 + lane) * 8);
      acc[nt] = __builtin_amdgcn_mfma_f32_16x16x32_bf16(ah, bh, acc[nt], 0, 0, 0);
      if (!A_BF16)
        acc[nt] = __builtin_amdgcn_mfma_f32_16x16x32_bf16(al, bh, acc[nt], 0, 0, 0);
      acc[nt] = __builtin_amdgcn_mfma_f32_16x16x32_bf16(ah, bl, acc[nt], 0, 0, 0);
    }
  }

// C/D layout (HW-verified): col = lane&15, row = (lane>>4)*4 + reg
#pragma unroll
  for (int nt = 0; nt < F; ++nt) {
    int c = col0 + nt * 16 + (lane & 15);
#pragma unroll
    for (int reg = 0; reg < 4; ++reg) {
      int r = brow + g * 4 + reg;
      if (r < M) {
        float v = acc[nt][reg];
        if (SIGMOID) v = 1.f / (1.f + __expf(-v));
        if (OUT_BF16) {
          ((unsigned short*)Cv)[(size_t)r * N + c] = f32_to_bf16_rne(v);
        } else {
          ((float*)Cv)[(size_t)r * N + c] = v;
        }
      }
    }
  }
}

// ---------------------------------------------------------------------------
// ELL fill body: 4B entry = (fp16(w) << 16) | u16(src), at dst*EW + cursor.
// ---------------------------------------------------------------------------
__device__ __forceinline__ void fill_body(int chunk, const int* __restrict__ src,
                                          const int* __restrict__ dst,
                                          const float* __restrict__ w,
                                          int* __restrict__ cnt,
                                          unsigned* __restrict__ ell) {
  int e = chunk * 256 + threadIdx.x;
  if (e < N_EDGES) {
    int d = dst[e];
    int slot = atomicAdd(&cnt[d], 1);
    if (slot < EW) {
      unsigned short hw = __half_as_ushort(__float2half_rn(w[e]));
      ell[(size_t)d * EW + slot] = ((unsigned)hw << 16) | (unsigned)src[e];
    }
  }
}

// P1 work item: {gemm, fill, fill} round-robin over GB1 + EDGE_BLOCKS items.
__device__ __forceinline__ void p1_body(int wk, const float* __restrict__ x,
                                        const short* __restrict__ W1h,
                                        const short* __restrict__ W1l,
                                        unsigned short* __restrict__ hb,
                                        const int* __restrict__ src,
                                        const int* __restrict__ dst,
                                        const float* __restrict__ w,
                                        int* __restrict__ cnt,
                                        unsigned* __restrict__ ell) {
  int g = wk / 3, r = wk % 3;
  if (r == 0) {
    gemm_body<NFEAT, NHID, false, false, true>(g, x, W1h, W1l, hb, N_NODES);
  } else {
    fill_body(2 * g + r - 1, src, dst, w, cnt, ell);
  }
}

// ---------------------------------------------------------------------------
// Gather SpMM body over ELL (4B desc), bf16 table. One wave per node; wave
// loads 64 descriptors in one coalesced dword/lane, broadcasts via shfl;
// inner loop: 8 gathers in flight.
// ---------------------------------------------------------------------------
template <bool LEAKY, bool OUT_BF16>
__device__ __forceinline__ void spmm_body(int bx, const unsigned* __restrict__ hb,
                                          const unsigned* __restrict__ ell,
                                          const int* __restrict__ cnt,
                                          void* __restrict__ outv) {
  int node = bx * 4 + (threadIdx.x >> 6);
  if (node >= N_NODES) return;
  int lane = threadIdx.x & 63;
  int n = cnt[node];
  if (n > EW) n = EW;
  unsigned mydesc = ell[(size_t)node * EW + lane];

  float ax = 0.f, ay = 0.f;
  int j = 0;
  for (; j + 8 <= n; j += 8) {
    unsigned dsc[8], u[8];
#pragma unroll
    for (int t = 0; t < 8; ++t) {
      dsc[t] = __shfl(mydesc, j + t, 64);
      u[t] = hb[(size_t)(dsc[t] & 0xffffu) * 64 + lane];
    }
#pragma unroll
    for (int t = 0; t < 8; ++t) {
      float wv = __half2float(__ushort_as_half((unsigned short)(dsc[t] >> 16)));
      ax += wv * __uint_as_float(u[t] << 16);
      ay += wv * __uint_as_float(u[t] & 0xffff0000u);
    }
  }
  for (; j < n; ++j) {
    unsigned dj = __shfl(mydesc, j, 64);
    unsigned uj = hb[(size_t)(dj & 0xffffu) * 64 + lane];
    float wv = __half2float(__ushort_as_half((unsigned short)(dj >> 16)));
    ax += wv * __uint_as_float(uj << 16);
    ay += wv * __uint_as_float(uj & 0xffff0000u);
  }

  if (LEAKY) {
    ax = (ax > 0.f) ? ax : 0.01f * ax;
    ay = (ay > 0.f) ? ay : 0.01f * ay;
  }
  if (OUT_BF16) {
    unsigned pk = ((unsigned)f32_to_bf16_rne(ay) << 16) | (unsigned)f32_to_bf16_rne(ax);
    ((unsigned*)outv)[(size_t)node * 64 + lane] = pk;
  } else {
    float2 o;
    o.x = ax;
    o.y = ay;
    ((float2*)outv)[(size_t)node * 64 + lane] = o;
  }
}

// ---------------------------------------------------------------------------
// Cooperative mega-kernel (grid-stride everything; no early returns).
// ---------------------------------------------------------------------------
__global__ __launch_bounds__(256, 4) void gcn_mega(
    const float* __restrict__ x, const int* __restrict__ edge_src,
    const int* __restrict__ edge_dst, const float* __restrict__ edge_w,
    const float* __restrict__ W1, const float* __restrict__ W2,
    const float* __restrict__ W3, float* __restrict__ Y, unsigned* __restrict__ ws) {
  cg::grid_group grid = cg::this_grid();
  const int G = gridDim.x;

  unsigned* hb = ws;                              // h1 then h2 (bf16x2 per u32)
  unsigned* x1b = hb + (size_t)N_NODES * 64;
  unsigned* ell = x1b + (size_t)N_NODES * 64;
  int* cnt = (int*)(ell + (size_t)N_NODES * EW);
  short* W1h = (short*)(cnt + N_NODES);
  short* W1l = W1h + NFEAT * NHID;
  short* W2h = W1l + NFEAT * NHID;
  short* W2l = W2h + NHID * NHID;
  short* W3h = W2l + NHID * NHID;
  short* W3l = W3h + NHID * NCLASS;
  float* x3 = Y + (size_t)N_NODES * NCLASS;

  for (int b = blockIdx.x; b < 224; b += G)
    prep_body(b, W1, W2, W3, W1h, W1l, W2h, W2l, W3h, W3l, cnt);
  grid.sync();

  for (int wk = blockIdx.x; wk < GB1 + EDGE_BLOCKS; wk += G)
    p1_body(wk, x, W1h, W1l, (unsigned short*)hb, edge_src, edge_dst, edge_w, cnt, ell);
  grid.sync();

  for (int b = blockIdx.x; b < NODE_BLOCKS; b += G)
    spmm_body<true, true>(b, hb, ell, cnt, x1b);
  grid.sync();

  for (int b = blockIdx.x; b < GB1; b += G)
    gemm_body<NHID, NHID, true, false, true>(b, x1b, W2h, W2l, hb, N_NODES);
  grid.sync();

  for (int b = blockIdx.x; b < NODE_BLOCKS; b += G)
    spmm_body<false, false>(b, hb, ell, cnt, x3);
  grid.sync();

  for (int b = blockIdx.x; b < GB1; b += G)
    gemm_body<NHID, NCLASS, false, true, false>(b, x3, W3h, W3l, Y, N_NODES);
}

// ---------------------------------------------------------------------------
// Fallback standalone kernels (round-5 structure, shared bodies).
// ---------------------------------------------------------------------------
__global__ __launch_bounds__(256) void prep_k(const float* __restrict__ W1,
                                              const float* __restrict__ W2,
                                              const float* __restrict__ W3, short* W1h,
                                              short* W1l, short* W2h, short* W2l,
                                              short* W3h, short* W3l,
                                              int* __restrict__ cnt) {
  prep_body(blockIdx.x, W1, W2, W3, W1h, W1l, W2h, W2l, W3h, W3l, cnt);
}

__global__ __launch_bounds__(256) void p1_k(const float* __restrict__ x,
                                            const short* __restrict__ W1h,
                                            const short* __restrict__ W1l,
                                            unsigned short* __restrict__ hb,
                                            const int* __restrict__ src,
                                            const int* __restrict__ dst,
                                            const float* __restrict__ w,
                                            int* __restrict__ cnt,
                                            unsigned* __restrict__ ell) {
  p1_body(blockIdx.x, x, W1h, W1l, hb, src, dst, w, cnt, ell);
}

template <bool LEAKY, bool OUT_BF16>
__global__ __launch_bounds__(256) void spmm_k(const unsigned* __restrict__ hb,
                                              const unsigned* __restrict__ ell,
                                              const int* __restrict__ cnt,
                                              void* __restrict__ outv) {
  spmm_body<LEAKY, OUT_BF16>(blockIdx.x, hb, ell, cnt, outv);
}

template <int K, int N, bool A_BF16, bool SIGMOID, bool OUT_BF16>
__global__ __launch_bounds__(256) void gemm_k(const void* __restrict__ Av,
                                              const short* __restrict__ Bh,
                                              const short* __restrict__ Bl,
                                              void* __restrict__ Cv, int M) {
  gemm_body<K, N, A_BF16, SIGMOID, OUT_BF16>(blockIdx.x, Av, Bh, Bl, Cv, M);
}

extern "C" void kernel_launch(void* const* d_in, const int* in_sizes, int n_in,
                              void* d_out, int out_size, void* d_ws, size_t ws_size,
                              hipStream_t stream) {
  const float* x = (const float*)d_in[0];
  const int* edge_src = (const int*)d_in[1];
  const int* edge_dst = (const int*)d_in[2];
  const float* edge_w = (const float*)d_in[3];
  const float* W1 = (const float*)d_in[4];
  const float* W2 = (const float*)d_in[5];
  const float* W3 = (const float*)d_in[6];
  float* Y = (float*)d_out;
  unsigned* ws = (unsigned*)d_ws;

  // workspace layout (mirrors device-side derivation)
  unsigned* hb = ws;
  unsigned* x1b = hb + (size_t)N_NODES * 64;
  unsigned* ell = x1b + (size_t)N_NODES * 64;
  int* cnt = (int*)(ell + (size_t)N_NODES * EW);
  short* W1h = (short*)(cnt + N_NODES);
  short* W1l = W1h + NFEAT * NHID;
  short* W2h = W1l + NFEAT * NHID;
  short* W2l = W2h + NHID * NHID;
  short* W3h = W2l + NHID * NHID;
  short* W3l = W3h + NHID * NCLASS;
  float* x3 = Y + (size_t)N_NODES * NCLASS;

  // --- try cooperative path, grid sized by occupancy API ---
  hipError_t rc = hipErrorUnknown;
  int maxB = 0, nCU = 0;
  if (hipOccupancyMaxActiveBlocksPerMultiprocessor(&maxB, (const void*)gcn_mega, 256,
                                                   0) == hipSuccess &&
      hipDeviceGetAttribute(&nCU, hipDeviceAttributeMultiprocessorCount, 0) ==
          hipSuccess &&
      maxB > 0 && nCU > 0) {
    dim3 grid(maxB * nCU);
    void* args[] = {(void*)&x,  (void*)&edge_src, (void*)&edge_dst,
                    (void*)&edge_w, (void*)&W1,   (void*)&W2,
                    (void*)&W3, (void*)&Y,        (void*)&ws};
    rc = hipLaunchCooperativeKernel((const void*)gcn_mega, grid, dim3(256), args, 0,
                                    stream);
  }
  if (rc == hipSuccess) return;

  // --- fallback: 6-dispatch pipeline (known-good structure) ---
  prep_k<<<224, 256, 0, stream>>>(W1, W2, W3, W1h, W1l, W2h, W2l, W3h, W3l, cnt);
  p1_k<<<GB1 + EDGE_BLOCKS, 256, 0, stream>>>(x, W1h, W1l, (unsigned short*)hb,
                                              edge_src, edge_dst, edge_w, cnt, ell);
  spmm_k<true, true><<<NODE_BLOCKS, 256, 0, stream>>>(hb, ell, cnt, x1b);
  gemm_k<NHID, NHID, true, false, true>
      <<<GB1, 256, 0, stream>>>(x1b, W2h, W2l, hb, N_NODES);
  spmm_k<false, false><<<NODE_BLOCKS, 256, 0, stream>>>(hb, ell, cnt, x3);
  gemm_k<NHID, NCLASS, false, true, false>
      <<<GB1, 256, 0, stream>>>(x3, W3h, W3l, Y, N_NODES);
}

// Round 8
// 261.030 us; speedup vs baseline: 2.6573x; 2.6573x over previous
//
#include <hip/hip_runtime.h>
#include <hip/hip_bf16.h>
#include <hip/hip_fp16.h>

// GCN forward on MI355X — 6-dispatch pipeline (cooperative mega-kernel was
// measured 3.4x SLOWER in round 7: grid.sync's device-scope fences destroy
// XCD-L2 locality; kernel boundaries are cheaper).
//
// x:[50000,256] f32, edges: 800000 (src,dst,w), W1:[256,128], W2:[128,128], W3:[128,64]
// out = concat(Y[50000,64], x3[50000,128]) f32
//
//   K0 prep:  zero cnt || pack W1/W2/W3 -> bf16 hi/lo (MFMA frag order)
//   K1 p1:    gemm1 h1 = x@W1 -> bf16  INTERLEAVED {gemm,fill,fill} with
//             ell_fill (4B entries: u16 src | fp16 w)
//   K2 spmm1: x1b = leaky(spmm(h1)) -> bf16
//   K3 gemm2: h2 = x1b @ W2 -> bf16 (A exact bf16, 2-term)
//   K4 spmm2: x3 -> d_out fp32  AND  x3b -> bf16 (dual write)
//   K5 gemm3: Y = sigmoid(x3b @ W3) -> d_out fp32 (A exact bf16, 2-term)

constexpr int N_NODES = 50000;
constexpr int N_EDGES = 800000;
constexpr int NFEAT = 256;
constexpr int NHID = 128;
constexpr int NCLASS = 64;
constexpr int EW = 64;  // ELL width (Poisson(16) => P(deg>=64) ~ 1e-18)

constexpr int GB1 = (N_NODES + 31) / 32;            // 1563 gemm M-tiles
constexpr int EDGE_BLOCKS = (N_EDGES + 255) / 256;  // 3125
constexpr int NODE_BLOCKS = (N_NODES + 3) / 4;      // 12500

typedef __attribute__((ext_vector_type(8))) short short8;
typedef __attribute__((ext_vector_type(4))) float f32x4;

__device__ __forceinline__ unsigned short f32_to_bf16_rne(float f) {
  unsigned u = __float_as_uint(f);
  unsigned r = u + 0x7fffu + ((u >> 16) & 1u);
  return (unsigned short)(r >> 16);
}
__device__ __forceinline__ float bf16_to_f32(unsigned short s) {
  return __uint_as_float(((unsigned)s) << 16);
}

// ---------------------------------------------------------------------------
// Pack W[K][N] fp32 -> hi/lo bf16 in MFMA fragment order.
// Frag f = kb*(N/16) + nt; lane l holds 8 elems: k = kb*32+(l>>4)*8+j, n = nt*16+(l&15).
// ---------------------------------------------------------------------------
template <int K, int N>
__device__ __forceinline__ void pack_dev(const float* __restrict__ W,
                                         short* __restrict__ Bh,
                                         short* __restrict__ Bl, int blk) {
  int idx = blk * 256 + threadIdx.x;
  constexpr int NFRAG = (K / 32) * (N / 16);
  if (idx >= NFRAG * 64) return;
  int l = idx & 63;
  int f = idx >> 6;
  int kb = f / (N / 16), nt = f % (N / 16);
  int g = l >> 4;
  int n = nt * 16 + (l & 15);
#pragma unroll
  for (int j = 0; j < 8; ++j) {
    int k = kb * 32 + g * 8 + j;
    float v = W[(size_t)k * N + n];
    unsigned short h = f32_to_bf16_rne(v);
    Bh[((size_t)f * 64 + l) * 8 + j] = (short)h;
    Bl[((size_t)f * 64 + l) * 8 + j] = (short)f32_to_bf16_rne(v - bf16_to_f32(h));
  }
}

__global__ __launch_bounds__(256) void prep_k(const float* __restrict__ W1,
                                              const float* __restrict__ W2,
                                              const float* __restrict__ W3, short* W1h,
                                              short* W1l, short* W2h, short* W2l,
                                              short* W3h, short* W3l,
                                              int* __restrict__ cnt) {
  int b = blockIdx.x;
  if (b < 196) {
    int i = b * 256 + threadIdx.x;
    if (i < N_NODES) cnt[i] = 0;
  } else if (b < 212) {
    pack_dev<NFEAT, NHID>(W1, W1h, W1l, b - 196);
  } else if (b < 220) {
    pack_dev<NHID, NHID>(W2, W2h, W2l, b - 212);
  } else {
    pack_dev<NHID, NCLASS>(W3, W3h, W3l, b - 220);
  }
}

// ---------------------------------------------------------------------------
// MFMA GEMM body: C[M,N] = A[M,K] @ W[K,N]
// A_BF16=0: A fp32, split3 (Ah@Bh + Al@Bh + Ah@Bl).  A_BF16=1: A bf16 exact, 2-term.
// 4 waves/block; wave = 16 rows x N/2 cols. bx in [0, ceil(M/32)).
// ---------------------------------------------------------------------------
template <int K, int N, bool A_BF16, bool SIGMOID, bool OUT_BF16>
__device__ __forceinline__ void gemm_body(int bx, const void* __restrict__ Av,
                                          const short* __restrict__ Bh,
                                          const short* __restrict__ Bl,
                                          void* __restrict__ Cv, int M) {
  constexpr int WCOL = N / 2;
  constexpr int F = WCOL / 16;
  const int tid = threadIdx.x;
  const int wid = tid >> 6;
  const int lane = tid & 63;
  const int g = lane >> 4;
  const int brow = bx * 32 + (wid >> 1) * 16;
  const int col0 = (wid & 1) * WCOL;
  const int row_a = brow + (lane & 15);

  f32x4 acc[F];
#pragma unroll
  for (int i = 0; i < F; ++i) acc[i] = (f32x4){0.f, 0.f, 0.f, 0.f};

#pragma unroll
  for (int kb = 0; kb < K / 32; ++kb) {
    const int ca = kb * 32 + g * 8;
    short8 ah, al;
    if (A_BF16) {
      const unsigned short* A = (const unsigned short*)Av;
      if (row_a < M) {
        ah = *reinterpret_cast<const short8*>(A + (size_t)row_a * K + ca);
      } else {
        ah = (short8){0, 0, 0, 0, 0, 0, 0, 0};
      }
    } else {
      const float* A = (const float*)Av;
      float4 a0 = {0.f, 0.f, 0.f, 0.f}, a1 = {0.f, 0.f, 0.f, 0.f};
      if (row_a < M) {
        a0 = *reinterpret_cast<const float4*>(A + (size_t)row_a * K + ca);
        a1 = *reinterpret_cast<const float4*>(A + (size_t)row_a * K + ca + 4);
      }
      float av[8] = {a0.x, a0.y, a0.z, a0.w, a1.x, a1.y, a1.z, a1.w};
#pragma unroll
      for (int j = 0; j < 8; ++j) {
        float v = av[j];
        unsigned short h = f32_to_bf16_rne(v);
        ah[j] = (short)h;
        al[j] = (short)f32_to_bf16_rne(v - bf16_to_f32(h));
      }
    }
#pragma unroll
    for (int nt = 0; nt < F; ++nt) {
      int f = kb * (N / 16) + (col0 >> 4) + nt;
      short8 bh = *reinterpret_cast<const short8*>(Bh + ((size_t)f * 64 + lane) * 8);
      short8 bl = *reinterpret_cast<const short8*>(Bl + ((size_t)f * 64 + lane) * 8);
      acc[nt] = __builtin_amdgcn_mfma_f32_16x16x32_bf16(ah, bh, acc[nt], 0, 0, 0);
      if (!A_BF16)
        acc[nt] = __builtin_amdgcn_mfma_f32_16x16x32_bf16(al, bh, acc[nt], 0, 0, 0);
      acc[nt] = __builtin_amdgcn_mfma_f32_16x16x32_bf16(ah, bl, acc[nt], 0, 0, 0);
    }
  }

// C/D layout (HW-verified): col = lane&15, row = (lane>>4)*4 + reg
#pragma unroll
  for (int nt = 0; nt < F; ++nt) {
    int c = col0 + nt * 16 + (lane & 15);
#pragma unroll
    for (int reg = 0; reg < 4; ++reg) {
      int r = brow + g * 4 + reg;
      if (r < M) {
        float v = acc[nt][reg];
        if (SIGMOID) v = 1.f / (1.f + __expf(-v));
        if (OUT_BF16) {
          ((unsigned short*)Cv)[(size_t)r * N + c] = f32_to_bf16_rne(v);
        } else {
          ((float*)Cv)[(size_t)r * N + c] = v;
        }
      }
    }
  }
}

template <int K, int N, bool A_BF16, bool SIGMOID, bool OUT_BF16>
__global__ __launch_bounds__(256) void gemm_k(const void* __restrict__ Av,
                                              const short* __restrict__ Bh,
                                              const short* __restrict__ Bl,
                                              void* __restrict__ Cv, int M) {
  gemm_body<K, N, A_BF16, SIGMOID, OUT_BF16>(blockIdx.x, Av, Bh, Bl, Cv, M);
}

// ---------------------------------------------------------------------------
// ELL fill body: 4B entry = (fp16(w) << 16) | u16(src), at dst*EW + cursor.
// ---------------------------------------------------------------------------
__device__ __forceinline__ void fill_body(int chunk, const int* __restrict__ src,
                                          const int* __restrict__ dst,
                                          const float* __restrict__ w,
                                          int* __restrict__ cnt,
                                          unsigned* __restrict__ ell) {
  int e = chunk * 256 + threadIdx.x;
  if (e < N_EDGES) {
    int d = dst[e];
    int slot = atomicAdd(&cnt[d], 1);
    if (slot < EW) {
      unsigned short hw = __half_as_ushort(__float2half_rn(w[e]));
      ell[(size_t)d * EW + slot] = ((unsigned)hw << 16) | (unsigned)src[e];
    }
  }
}

// K1: {gemm, fill, fill} round-robin over GB1 + EDGE_BLOCKS work items so the
// latency-bound scattered fill hides under gemm1's MFMA/stream on every CU.
__global__ __launch_bounds__(256) void p1_k(const float* __restrict__ x,
                                            const short* __restrict__ W1h,
                                            const short* __restrict__ W1l,
                                            unsigned short* __restrict__ hb,
                                            const int* __restrict__ src,
                                            const int* __restrict__ dst,
                                            const float* __restrict__ w,
                                            int* __restrict__ cnt,
                                            unsigned* __restrict__ ell) {
  int wk = blockIdx.x;
  int g = wk / 3, r = wk % 3;
  if (r == 0) {
    gemm_body<NFEAT, NHID, false, false, true>(g, x, W1h, W1l, hb, N_NODES);
  } else {
    fill_body(2 * g + r - 1, src, dst, w, cnt, ell);
  }
}

// ---------------------------------------------------------------------------
// Gather SpMM over ELL (4B desc), bf16 table. One wave per node; wave loads
// 64 descriptors in one coalesced dword/lane, zeroes the fp16 weight of empty
// slots, rounds the loop to x8 -> no tail; 8 gathers in flight.
// DUAL=1: write fp32 to out_f AND bf16 to out_b.
// ---------------------------------------------------------------------------
template <bool LEAKY, bool DUAL>
__device__ __forceinline__ void spmm_body(int bx, const unsigned* __restrict__ hb,
                                          const unsigned* __restrict__ ell,
                                          const int* __restrict__ cnt,
                                          unsigned* __restrict__ out_b,
                                          float2* __restrict__ out_f) {
  int node = bx * 4 + (threadIdx.x >> 6);
  if (node >= N_NODES) return;
  int lane = threadIdx.x & 63;
  int n = cnt[node];
  if (n > EW) n = EW;
  unsigned mydesc = ell[(size_t)node * EW + lane];
  if (lane >= n) mydesc &= 0xffffu;  // zero fp16 weight in empty slots
  int m = (n + 7) & ~7;

  float ax = 0.f, ay = 0.f;
  for (int j = 0; j < m; j += 8) {
    unsigned dsc[8], u[8];
#pragma unroll
    for (int t = 0; t < 8; ++t) {
      dsc[t] = __shfl(mydesc, j + t, 64);
      u[t] = hb[(size_t)(dsc[t] & 0xffffu) * 64 + lane];
    }
#pragma unroll
    for (int t = 0; t < 8; ++t) {
      float wv = __half2float(__ushort_as_half((unsigned short)(dsc[t] >> 16)));
      ax += wv * __uint_as_float(u[t] << 16);
      ay += wv * __uint_as_float(u[t] & 0xffff0000u);
    }
  }

  if (LEAKY) {
    ax = (ax > 0.f) ? ax : 0.01f * ax;
    ay = (ay > 0.f) ? ay : 0.01f * ay;
  }
  unsigned pk = ((unsigned)f32_to_bf16_rne(ay) << 16) | (unsigned)f32_to_bf16_rne(ax);
  if (DUAL) {
    float2 o;
    o.x = ax;
    o.y = ay;
    out_f[(size_t)node * 64 + lane] = o;
    out_b[(size_t)node * 64 + lane] = pk;
  } else {
    out_b[(size_t)node * 64 + lane] = pk;
  }
}

template <bool LEAKY, bool DUAL>
__global__ __launch_bounds__(256) void spmm_k(const unsigned* __restrict__ hb,
                                              const unsigned* __restrict__ ell,
                                              const int* __restrict__ cnt,
                                              unsigned* __restrict__ out_b,
                                              float2* __restrict__ out_f) {
  spmm_body<LEAKY, DUAL>(blockIdx.x, hb, ell, cnt, out_b, out_f);
}

extern "C" void kernel_launch(void* const* d_in, const int* in_sizes, int n_in,
                              void* d_out, int out_size, void* d_ws, size_t ws_size,
                              hipStream_t stream) {
  const float* x = (const float*)d_in[0];
  const int* edge_src = (const int*)d_in[1];
  const int* edge_dst = (const int*)d_in[2];
  const float* edge_w = (const float*)d_in[3];
  const float* W1 = (const float*)d_in[4];
  const float* W2 = (const float*)d_in[5];
  const float* W3 = (const float*)d_in[6];
  float* Y = (float*)d_out;
  float* x3 = Y + (size_t)N_NODES * NCLASS;

  // workspace layout (u32 units, 16B-aligned chunks)
  unsigned* hb = (unsigned*)d_ws;                  // 12.8 MB (h1 then h2)
  unsigned* x1b = hb + (size_t)N_NODES * 64;       // 12.8 MB
  unsigned* x3b = x1b + (size_t)N_NODES * 64;      // 12.8 MB (bf16 copy of x3)
  unsigned* ell = x3b + (size_t)N_NODES * 64;      // 12.8 MB (4B entries)
  int* cnt = (int*)(ell + (size_t)N_NODES * EW);   // 200 KB
  short* W1h = (short*)(cnt + N_NODES);            // 64 KB
  short* W1l = W1h + NFEAT * NHID;
  short* W2h = W1l + NFEAT * NHID;
  short* W2l = W2h + NHID * NHID;
  short* W3h = W2l + NHID * NHID;
  short* W3l = W3h + NHID * NCLASS;

  // K0: zero cnt || pack weights
  prep_k<<<224, 256, 0, stream>>>(W1, W2, W3, W1h, W1l, W2h, W2l, W3h, W3l, cnt);

  // K1: h1 = x @ W1 -> bf16  ||  ELL fill (interleaved)
  p1_k<<<GB1 + EDGE_BLOCKS, 256, 0, stream>>>(x, W1h, W1l, (unsigned short*)hb,
                                              edge_src, edge_dst, edge_w, cnt, ell);

  // K2: x1b = leaky(spmm(h1)) -> bf16
  spmm_k<true, false><<<NODE_BLOCKS, 256, 0, stream>>>(hb, ell, cnt, x1b, nullptr);

  // K3: h2 = x1b @ W2 -> bf16 (reuse hb)
  gemm_k<NHID, NHID, true, false, true>
      <<<GB1, 256, 0, stream>>>(x1b, W2h, W2l, hb, N_NODES);

  // K4: x3 = spmm(h2) -> d_out fp32 + x3b bf16
  spmm_k<false, true>
      <<<NODE_BLOCKS, 256, 0, stream>>>(hb, ell, cnt, x3b, (float2*)x3);

  // K5: Y = sigmoid(x3b @ W3) -> d_out fp32 (A exact bf16, 2-term)
  gemm_k<NHID, NCLASS, true, true, false>
      <<<GB1, 256, 0, stream>>>(x3b, W3h, W3l, Y, N_NODES);
}